// Round 1
// baseline (196.568 us; speedup 1.0000x reference)
//
#include <hip/hip_runtime.h>

#define NB   32
#define TMAX 512
#define DDIM 384
#define TOUT (TMAX * 7)      // 3584
#define D4   (DDIM / 4)      // 96 float4 per frame
#define FPB  32              // frames per block
#define NTH  256             // threads per block (4 waves)

// Fused kernel: every block recomputes its batch's masked duration cumsum
// (512 elements, shuffle-scan, ~2 barriers), binary-searches its FPB frames,
// and writes FPB*96 float4 = 48 KB of contiguous output.
// Grid: (TOUT/FPB, B) = (112, 32) = 3584 blocks.
__global__ __launch_bounds__(NTH) void lr_fused_kernel(
        const float4* __restrict__ xs,
        const int*    __restrict__ ds,
        const int*    __restrict__ ilens,
        float4*       __restrict__ out) {
    __shared__ int s_cum[TMAX];
    __shared__ int s_wsum[NTH / 64];
    __shared__ int s_idx[FPB];

    const int b    = blockIdx.y;
    const int f0   = blockIdx.x * FPB;
    const int t    = threadIdx.x;
    const int lane = t & 63;
    const int wid  = t >> 6;

    const int len = ilens[b];

    // ---- masked cumsum of ds: 512 elems, 2 per thread -------------------
    // elements e0 = 2t, e1 = 2t+1
    const int2 dv = reinterpret_cast<const int2*>(ds + b * TMAX)[t];
    const int e0 = 2 * t, e1 = 2 * t + 1;
    const int a = (e0 < len) ? dv.x : 0;
    const int c = (e1 < len) ? dv.y : 0;

    // in-register inclusive scan of pair-sums across the wave (64 lanes)
    int x = a + c;
#pragma unroll
    for (int off = 1; off < 64; off <<= 1) {
        int v = __shfl_up(x, off);
        if (lane >= off) x += v;
    }
    if (lane == 63) s_wsum[wid] = x;
    __syncthreads();
    int prev = 0;
#pragma unroll
    for (int w = 0; w < NTH / 64; ++w)
        if (w < wid) prev += s_wsum[w];
    const int inc = x + prev;       // inclusive cumsum through element e1
    s_cum[e1] = inc;
    s_cum[e0] = inc - c;
    __syncthreads();

    int total = s_cum[TMAX - 1];
    if (total == 0) {               // uniform branch per block
        // fallback d = mask  =>  cum[t] = min(t+1, len), closed form
        __syncthreads();            // everyone has read s_cum[TMAX-1]
        s_cum[e0] = min(e0 + 1, len);
        s_cum[e1] = min(e1 + 1, len);
        total = len;
        __syncthreads();
    }

    // ---- searchsorted(cum, f, side='right') for this block's frames -----
    if (t < FPB) {
        const int f = f0 + t;
        int lo = 0, hi = TMAX;
        while (lo < hi) {
            int mid = (lo + hi) >> 1;
            if (s_cum[mid] > f) hi = mid; else lo = mid + 1;
        }
        s_idx[t] = (lo < TMAX) ? lo : (TMAX - 1);
    }
    __syncthreads();

    // ---- expand: FPB*96 = 3072 float4, 12 per thread, fully contiguous --
    const int base_out = (b * TOUT + f0) * D4;
    const int base_xs  = b * TMAX * D4;
#pragma unroll
    for (int i = 0; i < FPB * D4 / NTH; ++i) {
        const int l   = i * NTH + t;    // 0..3071, contiguous across threads
        const int fl  = l / D4;         // local frame 0..31
        const int col = l - fl * D4;    // 0..95
        float4 v = make_float4(0.f, 0.f, 0.f, 0.f);
        if (f0 + fl < total)
            v = xs[base_xs + s_idx[fl] * D4 + col];
        out[base_out + l] = v;
    }
}

extern "C" void kernel_launch(void* const* d_in, const int* in_sizes, int n_in,
                              void* d_out, int out_size, void* d_ws, size_t ws_size,
                              hipStream_t stream) {
    const float* xs    = (const float*)d_in[0];
    const int*   ds    = (const int*)d_in[1];
    const int*   ilens = (const int*)d_in[2];
    float*       out   = (float*)d_out;

    dim3 grid(TOUT / FPB, NB);   // 112 x 32
    lr_fused_kernel<<<grid, NTH, 0, stream>>>(
        (const float4*)xs, ds, ilens, (float4*)out);
}